// Round 3
// baseline (214.571 us; speedup 1.0000x reference)
//
#include <hip/hip_runtime.h>
#include <math.h>

#define NRES 22

// LDS layout (float indices). Odd strides -> bank-spread per-lane reads.
//  rigT: combo*97 + f*12 + k   (66 combos, 8 frames, 12 floats; 97 mod 32 = 1)
//  rigG: combo*73 + j          (72 floats/combo; 73 mod 32 = 9)
//  tdep: rt*9 + i (int)        rdep: rt*25 + a (int)
//  strm: reused 4352-float buffer (o0 tile, then o1+pos tiles)
#define L_RIGT 0
#define L_RIGG 6402
#define L_TDEP 11220
#define L_RDEP 11418
#define L_STRM 11968
#define L_TOT  16320   // 65,280 bytes -> 2 blocks/CU

// Select fr[d] (d in 0..7) into P via a 3-level cndmask tree (registers only).
__device__ __forceinline__ void sel8(const float (&fr)[8][12], int d, float (&P)[12]) {
    const bool b0 = (d & 1) != 0;
    const bool b1 = (d & 2) != 0;
    const bool b2 = (d & 4) != 0;
#pragma unroll
    for (int k = 0; k < 12; ++k) {
        float a01 = b0 ? fr[1][k] : fr[0][k];
        float a23 = b0 ? fr[3][k] : fr[2][k];
        float a45 = b0 ? fr[5][k] : fr[4][k];
        float a67 = b0 ? fr[7][k] : fr[6][k];
        float b03 = b1 ? a23 : a01;
        float b47 = b1 ? a67 : a45;
        P[k] = b2 ? b47 : b03;
    }
}

__device__ __forceinline__ void apply_point(const float (&F)[12], float x, float y, float z,
                                            float &px, float &py, float &pz) {
    px = fmaf(F[0], x, fmaf(F[1], y, fmaf(F[2], z, F[9])));
    py = fmaf(F[3], x, fmaf(F[4], y, fmaf(F[5], z, F[10])));
    pz = fmaf(F[6], x, fmaf(F[7], y, fmaf(F[8], z, F[11])));
}

extern "C" __global__ __launch_bounds__(256)
void model_kernel(const float* __restrict__ o0,     // (N,17)
                  const float* __restrict__ o1,     // (N,3,3)
                  const float* __restrict__ pos,    // (N,3)
                  const int*   __restrict__ ssArr,  // (N,)
                  const int*   __restrict__ rtArr,  // (N,)
                  const float* __restrict__ rigT,   // (3,22,8,4,3)
                  const float* __restrict__ rigG,   // (3,22,24,3)
                  const int*   __restrict__ tdepArr,// (22,8)
                  const int*   __restrict__ rdepArr,// (22,24)
                  float* __restrict__ outR,         // (N,24,3)
                  float* __restrict__ outF,         // (N,4,3)
                  int N)
{
    __shared__ float lds[L_TOT];
    int* ilds = (int*)lds;

    const int tid = threadIdx.x;
    const int R0  = blockIdx.x << 8;
    const int cnt = min(256, N - R0);

    // ---- stage tables (coalesced global float4, padded LDS layout) ----
    for (int i = tid; i < 1584; i += 256) {           // rigT: 6336 floats
        float4 v = ((const float4*)rigT)[i];
        int g = i << 2;
        int c = g / 96;                                // rows are 96 floats, 96%4==0
        int base = L_RIGT + c * 97 + (g - c * 96);
        lds[base] = v.x; lds[base + 1] = v.y; lds[base + 2] = v.z; lds[base + 3] = v.w;
    }
    for (int i = tid; i < 1188; i += 256) {           // rigG: 4752 floats
        float4 v = ((const float4*)rigG)[i];
        int g = i << 2;
        int c = g / 72;                                // rows are 72 floats, 72%4==0
        int base = L_RIGG + c * 73 + (g - c * 72);
        lds[base] = v.x; lds[base + 1] = v.y; lds[base + 2] = v.z; lds[base + 3] = v.w;
    }
    for (int i = tid; i < 176; i += 256) {            // tdep 22x8
        int r = i >> 3;
        ilds[L_TDEP + r * 9 + (i & 7)] = tdepArr[i];
    }
    for (int i = tid; i < 528; i += 256) {            // rdep 22x24
        int r = i / 24;
        ilds[L_RDEP + r * 25 + (i - r * 24)] = rdepArr[i];
    }
    // ---- stage o0 tile (coalesced) ----
    if (cnt == 256) {
        const float4* src = (const float4*)(o0 + (size_t)R0 * 17);
        float4* dst = (float4*)(lds + L_STRM);
        for (int i = tid; i < 1088; i += 256) dst[i] = src[i];
    } else {
        for (int i = tid; i < cnt * 17; i += 256) lds[L_STRM + i] = o0[(size_t)R0 * 17 + i];
    }
    __syncthreads();

    // ---- torsion cos/sin from LDS (stride 17 -> conflict-free) ----
    float c7[7], s7[7];
    {
        const float* my = lds + L_STRM + tid * 17;
        if (tid < cnt) {
#pragma unroll
            for (int t = 0; t < 7; ++t) {
                float cr = my[2 * t], sr = my[2 * t + 1];
                float inv = rsqrtf(fmaxf(cr * cr + sr * sr, 1e-12f));
                c7[t] = cr * inv;
                s7[t] = sr * inv;
            }
        }
    }
    __syncthreads();

    // ---- restage stream buffer with o1 + pos ----
    if (cnt == 256) {
        const float4* s1 = (const float4*)(o1 + (size_t)R0 * 9);
        float4* d1 = (float4*)(lds + L_STRM);
        for (int i = tid; i < 576; i += 256) d1[i] = s1[i];
        const float4* s2 = (const float4*)(pos + (size_t)R0 * 3);
        float4* d2 = (float4*)(lds + L_STRM + 2304);
        for (int i = tid; i < 192; i += 256) d2[i] = s2[i];
    } else {
        for (int i = tid; i < cnt * 9; i += 256) lds[L_STRM + i] = o1[(size_t)R0 * 9 + i];
        for (int i = tid; i < cnt * 3; i += 256) lds[L_STRM + 2304 + i] = pos[(size_t)R0 * 3 + i];
    }
    __syncthreads();

    if (tid >= cnt) return;
    const int res = R0 + tid;

    const int s  = ssArr[res];
    const int rt = rtArr[res];
    const int cmb = s * NRES + rt;
    const float* Tp = lds + L_RIGT + cmb * 97;
    const float* Gp = lds + L_RIGG + cmb * 73;
    const int*   td = ilds + L_TDEP + rt * 9;
    const int*   rd = ilds + L_RDEP + rt * 25;

    // ---- backbone frame (Gram-Schmidt) from LDS ----
    const float* o1p = lds + L_STRM + tid * 9;
    const float* pp  = lds + L_STRM + 2304 + tid * 3;
    float r0x = o1p[0], r0y = o1p[1], r0z = o1p[2];
    float v1x = o1p[3], v1y = o1p[4], v1z = o1p[5];
    float t2x = o1p[6], t2y = o1p[7], t2z = o1p[8];
    float inv0 = rsqrtf(fmaxf(r0x * r0x + r0y * r0y + r0z * r0z, 1e-12f));
    float e0x = r0x * inv0, e0y = r0y * inv0, e0z = r0z * inv0;
    float d01 = e0x * v1x + e0y * v1y + e0z * v1z;
    float u1x = v1x - e0x * d01, u1y = v1y - e0y * d01, u1z = v1z - e0z * d01;
    float inv1 = rsqrtf(fmaxf(u1x * u1x + u1y * u1y + u1z * u1z, 1e-12f));
    float e1x = u1x * inv1, e1y = u1y * inv1, e1z = u1z * inv1;
    float e2x = e0y * e1z - e0z * e1y;
    float e2y = e0z * e1x - e0x * e1z;
    float e2z = e0x * e1y - e0y * e1x;
    float btx = 0.1f * t2x + pp[0];
    float bty = 0.1f * t2y + pp[1];
    float btz = 0.1f * t2z + pp[2];

    float fr[8][12];

    // frame 0 = combine(T0, [rot(cols e0,e1,e2); bt])
#pragma unroll
    for (int i = 0; i < 3; ++i) {
        float a = Tp[i * 3 + 0], b = Tp[i * 3 + 1], d = Tp[i * 3 + 2];
        fr[0][i * 3 + 0] = a * e0x + b * e0y + d * e0z;
        fr[0][i * 3 + 1] = a * e1x + b * e1y + d * e1z;
        fr[0][i * 3 + 2] = a * e2x + b * e2y + d * e2z;
        fr[0][9 + i]     = a * btx + b * bty + d * btz + Tp[9 + i];
    }

    // frames 1..7 = combine(Tf, rotX(c,s))
#pragma unroll
    for (int f = 1; f < 8; ++f) {
        const float* Tf = Tp + f * 12;
        float cc = c7[f - 1], ssn = s7[f - 1];
#pragma unroll
        for (int i = 0; i < 3; ++i) {
            float m1 = Tf[i * 3 + 1], m2 = Tf[i * 3 + 2];
            fr[f][i * 3 + 0] = Tf[i * 3 + 0];
            fr[f][i * 3 + 1] = m1 * cc + m2 * ssn;
            fr[f][i * 3 + 2] = m2 * cc - m1 * ssn;
            fr[f][9 + i]     = Tf[9 + i];
        }
    }

    // ---- sequential dependency chain ----
#pragma unroll
    for (int i = 1; i < 8; ++i) {
        float P[12];
        sel8(fr, td[i] & 7, P);
        float Y[12];
#pragma unroll
        for (int k = 0; k < 12; ++k) Y[k] = fr[i][k];
#pragma unroll
        for (int r = 0; r < 3; ++r) {
            float a = P[r * 3 + 0], b = P[r * 3 + 1], d = P[r * 3 + 2];
#pragma unroll
            for (int j = 0; j < 3; ++j)
                fr[i][r * 3 + j] = a * Y[j] + b * Y[3 + j] + d * Y[6 + j];
            fr[i][9 + r] = a * Y[9] + b * Y[10] + d * Y[11] + P[9 + r];
        }
    }

    // ---- atoms: 24 point transforms, coalesced float4 stores ----
    float4* OR4 = (float4*)(outR + (size_t)res * 72);
#pragma unroll
    for (int ck = 0; ck < 6; ++ck) {
        int r0 = rd[ck * 4 + 0] & 7, r1 = rd[ck * 4 + 1] & 7;
        int r2 = rd[ck * 4 + 2] & 7, r3 = rd[ck * 4 + 3] & 7;
        const float* g = Gp + ck * 12;
        float P[12];
        float p0x, p0y, p0z, p1x, p1y, p1z, p2x, p2y, p2z, p3x, p3y, p3z;
        sel8(fr, r0, P); apply_point(P, g[0], g[1], g[2],  p0x, p0y, p0z);
        sel8(fr, r1, P); apply_point(P, g[3], g[4], g[5],  p1x, p1y, p1z);
        sel8(fr, r2, P); apply_point(P, g[6], g[7], g[8],  p2x, p2y, p2z);
        sel8(fr, r3, P); apply_point(P, g[9], g[10], g[11], p3x, p3y, p3z);
        OR4[ck * 3 + 0] = make_float4(p0x, p0y, p0z, p1x);
        OR4[ck * 3 + 1] = make_float4(p1y, p1z, p2x, p2y);
        OR4[ck * 3 + 2] = make_float4(p2z, p3x, p3y, p3z);
    }

    // ---- second output: opr[:,0] ----
    float4* OF4 = (float4*)(outF + (size_t)res * 12);
    OF4[0] = make_float4(fr[0][0], fr[0][1], fr[0][2], fr[0][3]);
    OF4[1] = make_float4(fr[0][4], fr[0][5], fr[0][6], fr[0][7]);
    OF4[2] = make_float4(fr[0][8], fr[0][9], fr[0][10], fr[0][11]);
}

extern "C" void kernel_launch(void* const* d_in, const int* in_sizes, int n_in,
                              void* d_out, int out_size, void* d_ws, size_t ws_size,
                              hipStream_t stream) {
    const float* o0   = (const float*)d_in[0];
    const float* o1   = (const float*)d_in[1];
    const float* pos  = (const float*)d_in[2];
    const int*   ssA  = (const int*)d_in[3];
    const int*   rtA  = (const int*)d_in[4];
    const float* rigT = (const float*)d_in[5];
    const float* rigG = (const float*)d_in[6];
    const int*   tdep = (const int*)d_in[7];
    const int*   rdep = (const int*)d_in[8];

    const int N = in_sizes[3]; // ss has N elements
    float* outR = (float*)d_out;
    float* outF = (float*)d_out + (size_t)N * 72;

    const int block = 256;
    const int grid  = (N + block - 1) / block;
    model_kernel<<<grid, block, 0, stream>>>(o0, o1, pos, ssA, rtA, rigT, rigG,
                                             tdep, rdep, outR, outF, N);
}

// Round 4
// 196.475 us; speedup vs baseline: 1.0921x; 1.0921x over previous
//
#include <hip/hip_runtime.h>
#include <hip/hip_bf16.h>
#include <math.h>

#define NRES 22

__device__ __forceinline__ void sel8(const float (&fr)[8][12], int d, float (&P)[12]) {
    const bool b0 = (d & 1) != 0;
    const bool b1 = (d & 2) != 0;
    const bool b2 = (d & 4) != 0;
#pragma unroll
    for (int k = 0; k < 12; ++k) {
        float a01 = b0 ? fr[1][k] : fr[0][k];
        float a23 = b0 ? fr[3][k] : fr[2][k];
        float a45 = b0 ? fr[5][k] : fr[4][k];
        float a67 = b0 ? fr[7][k] : fr[6][k];
        float b03 = b1 ? a23 : a01;
        float b47 = b1 ? a67 : a45;
        P[k] = b2 ? b47 : b03;
    }
}

__device__ __forceinline__ void apply_point(const float (&F)[12], float x, float y, float z,
                                            float &px, float &py, float &pz) {
    px = fmaf(F[0], x, fmaf(F[1], y, fmaf(F[2], z, F[9])));
    py = fmaf(F[3], x, fmaf(F[4], y, fmaf(F[5], z, F[10])));
    pz = fmaf(F[6], x, fmaf(F[7], y, fmaf(F[8], z, F[11])));
}

__device__ __forceinline__ unsigned pk2(float a, float b) {
    __hip_bfloat162 h = __float22bfloat162_rn(make_float2(a, b));
    union { __hip_bfloat162 h; unsigned u; } cv; cv.h = h;
    return cv.u;  // low 16 = a, high 16 = b
}

// ---------------- Kernel A: frame chain, dump bf16 frames to scratch --------
// Computes the residue frame chain in registers (as R1), writes outF (f32)
// and all 8 frames as packed bf16 (48 dwords = 192 B/residue) to d_ws.
extern "C" __global__ __launch_bounds__(256)
void chain_kernel(const float* __restrict__ o0,     // (N,17)
                  const float* __restrict__ o1,     // (N,3,3)
                  const float* __restrict__ pos,    // (N,3)
                  const int*   __restrict__ ssArr,  // (N,)
                  const int*   __restrict__ rtArr,  // (N,)
                  const float* __restrict__ rigT,   // (3,22,8,4,3)
                  const int*   __restrict__ tdepArr,// (22,8)
                  unsigned* __restrict__ framesPk,  // (N,48) dwords
                  float* __restrict__ outF,         // (N,4,3)
                  int N)
{
    const int res = blockIdx.x * 256 + threadIdx.x;
    if (res >= N) return;

    const int s  = ssArr[res];
    const int rt = rtArr[res];

    // torsion cos/sin
    float c[7], sn[7];
    const float* o0p = o0 + (size_t)res * 17;
#pragma unroll
    for (int t = 0; t < 7; ++t) {
        float cr = o0p[2 * t], sr = o0p[2 * t + 1];
        float inv = rsqrtf(fmaxf(cr * cr + sr * sr, 1e-12f));
        c[t]  = cr * inv;
        sn[t] = sr * inv;
    }

    // backbone frame (Gram-Schmidt)
    const float* o1p = o1 + (size_t)res * 9;
    float r0x = o1p[0], r0y = o1p[1], r0z = o1p[2];
    float v1x = o1p[3], v1y = o1p[4], v1z = o1p[5];
    float t2x = o1p[6], t2y = o1p[7], t2z = o1p[8];
    float inv0 = rsqrtf(fmaxf(r0x * r0x + r0y * r0y + r0z * r0z, 1e-12f));
    float e0x = r0x * inv0, e0y = r0y * inv0, e0z = r0z * inv0;
    float d01 = e0x * v1x + e0y * v1y + e0z * v1z;
    float u1x = v1x - e0x * d01, u1y = v1y - e0y * d01, u1z = v1z - e0z * d01;
    float inv1 = rsqrtf(fmaxf(u1x * u1x + u1y * u1y + u1z * u1z, 1e-12f));
    float e1x = u1x * inv1, e1y = u1y * inv1, e1z = u1z * inv1;
    float e2x = e0y * e1z - e0z * e1y;
    float e2y = e0z * e1x - e0x * e1z;
    float e2z = e0x * e1y - e0y * e1x;
    const float* pp = pos + (size_t)res * 3;
    float btx = 0.1f * t2x + pp[0];
    float bty = 0.1f * t2y + pp[1];
    float btz = 0.1f * t2z + pp[2];

    const int sr22 = s * NRES + rt;
    const float4* T4 = (const float4*)rigT + (size_t)sr22 * 24;

    float fr[8][12];

    {   // frame 0 = combine(T0, [rot(cols e0,e1,e2); bt])
        float4 q0 = T4[0], q1 = T4[1], q2 = T4[2];
        float T0[12] = {q0.x, q0.y, q0.z, q0.w, q1.x, q1.y, q1.z, q1.w,
                        q2.x, q2.y, q2.z, q2.w};
#pragma unroll
        for (int i = 0; i < 3; ++i) {
            float a = T0[i * 3 + 0], b = T0[i * 3 + 1], d = T0[i * 3 + 2];
            fr[0][i * 3 + 0] = a * e0x + b * e0y + d * e0z;
            fr[0][i * 3 + 1] = a * e1x + b * e1y + d * e1z;
            fr[0][i * 3 + 2] = a * e2x + b * e2y + d * e2z;
            fr[0][9 + i]     = a * btx + b * bty + d * btz + T0[9 + i];
        }
    }

#pragma unroll
    for (int f = 1; f < 8; ++f) {   // combine(Tf, rotX(c,s))
        float4 q0 = T4[f * 3 + 0], q1 = T4[f * 3 + 1], q2 = T4[f * 3 + 2];
        float Tf[12] = {q0.x, q0.y, q0.z, q0.w, q1.x, q1.y, q1.z, q1.w,
                        q2.x, q2.y, q2.z, q2.w};
        float cc = c[f - 1], ssn = sn[f - 1];
#pragma unroll
        for (int i = 0; i < 3; ++i) {
            float m1 = Tf[i * 3 + 1], m2 = Tf[i * 3 + 2];
            fr[f][i * 3 + 0] = Tf[i * 3 + 0];
            fr[f][i * 3 + 1] = m1 * cc + m2 * ssn;
            fr[f][i * 3 + 2] = m2 * cc - m1 * ssn;
            fr[f][9 + i]     = Tf[9 + i];
        }
    }

    // sequential dependency chain
    int tdv[8];
    {
        const int4* tdq = (const int4*)(tdepArr + rt * 8);
        int4 a = tdq[0], b = tdq[1];
        tdv[0] = a.x; tdv[1] = a.y; tdv[2] = a.z; tdv[3] = a.w;
        tdv[4] = b.x; tdv[5] = b.y; tdv[6] = b.z; tdv[7] = b.w;
    }
#pragma unroll
    for (int i = 1; i < 8; ++i) {
        float P[12];
        sel8(fr, tdv[i] & 7, P);
        float Y[12];
#pragma unroll
        for (int k = 0; k < 12; ++k) Y[k] = fr[i][k];
#pragma unroll
        for (int r = 0; r < 3; ++r) {
            float a = P[r * 3 + 0], b = P[r * 3 + 1], d = P[r * 3 + 2];
#pragma unroll
            for (int j = 0; j < 3; ++j)
                fr[i][r * 3 + j] = a * Y[j] + b * Y[3 + j] + d * Y[6 + j];
            fr[i][9 + r] = a * Y[9] + b * Y[10] + d * Y[11] + P[9 + r];
        }
    }

    // outF (f32, from fr[0])
    float4* OF4 = (float4*)(outF + (size_t)res * 12);
    OF4[0] = make_float4(fr[0][0], fr[0][1], fr[0][2], fr[0][3]);
    OF4[1] = make_float4(fr[0][4], fr[0][5], fr[0][6], fr[0][7]);
    OF4[2] = make_float4(fr[0][8], fr[0][9], fr[0][10], fr[0][11]);

    // dump 8 frames as bf16: 96 floats -> 48 dwords -> 12 dwordx4 (contiguous per thread)
    const float* fl = &fr[0][0];
    uint4* dst = (uint4*)(framesPk + (size_t)res * 48);
#pragma unroll
    for (int j = 0; j < 12; ++j) {
        uint4 w;
        w.x = pk2(fl[8 * j + 0], fl[8 * j + 1]);
        w.y = pk2(fl[8 * j + 2], fl[8 * j + 3]);
        w.z = pk2(fl[8 * j + 4], fl[8 * j + 5]);
        w.w = pk2(fl[8 * j + 6], fl[8 * j + 7]);
        dst[j] = w;
    }
}

// ---------------- Kernel B: one thread per atom ----------------------------
extern "C" __global__ __launch_bounds__(256)
void atoms_kernel(const int*   __restrict__ ssArr,
                  const int*   __restrict__ rtArr,
                  const float* __restrict__ rigG,   // (3,22,24,3)
                  const int*   __restrict__ rdepArr,// (22,24)
                  const unsigned* __restrict__ framesPk, // (N,48)
                  float* __restrict__ outR,         // (N,24,3)
                  int N)
{
    const int gid = blockIdx.x * 256 + threadIdx.x;
    if (gid >= N * 24) return;
    const unsigned t8 = (unsigned)gid >> 3;
    const unsigned res = (unsigned)(((unsigned long long)t8 * 0xAAAAAAABull) >> 33); // gid/24
    const int a = gid - (int)res * 24;

    const int s  = ssArr[res];
    const int rt = rtArr[res];
    const int cmb = s * NRES + rt;
    const int f = rdepArr[rt * 24 + a] & 7;

    // frame: 24 bf16 = 6 dwords, 8B-aligned -> 3 x uint2
    const uint2* fp = (const uint2*)(framesPk + (size_t)res * 48 + f * 6);
    uint2 u0 = fp[0], u1 = fp[1], u2 = fp[2];
    float F[12];
    F[0]  = __uint_as_float(u0.x << 16);  F[1]  = __uint_as_float(u0.x & 0xFFFF0000u);
    F[2]  = __uint_as_float(u0.y << 16);  F[3]  = __uint_as_float(u0.y & 0xFFFF0000u);
    F[4]  = __uint_as_float(u1.x << 16);  F[5]  = __uint_as_float(u1.x & 0xFFFF0000u);
    F[6]  = __uint_as_float(u1.y << 16);  F[7]  = __uint_as_float(u1.y & 0xFFFF0000u);
    F[8]  = __uint_as_float(u2.x << 16);  F[9]  = __uint_as_float(u2.x & 0xFFFF0000u);
    F[10] = __uint_as_float(u2.y << 16);  F[11] = __uint_as_float(u2.y & 0xFFFF0000u);

    const float* g = rigG + (size_t)cmb * 72 + a * 3;
    float gx = g[0], gy = g[1], gz = g[2];

    float px = fmaf(F[0], gx, fmaf(F[1], gy, fmaf(F[2], gz, F[9])));
    float py = fmaf(F[3], gx, fmaf(F[4], gy, fmaf(F[5], gz, F[10])));
    float pz = fmaf(F[6], gx, fmaf(F[7], gy, fmaf(F[8], gz, F[11])));

    float* o = outR + (size_t)gid * 3;
    o[0] = px; o[1] = py; o[2] = pz;
}

// ---------------- Fallback: monolithic R1 kernel (if ws too small) ---------
extern "C" __global__ __launch_bounds__(256)
void model_kernel_mono(const float* __restrict__ o0, const float* __restrict__ o1,
                       const float* __restrict__ pos, const int* __restrict__ ssArr,
                       const int* __restrict__ rtArr, const float* __restrict__ rigT,
                       const float* __restrict__ rigG, const int* __restrict__ tdepArr,
                       const int* __restrict__ rdepArr, float* __restrict__ outR,
                       float* __restrict__ outF, int N)
{
    const int res = blockIdx.x * 256 + threadIdx.x;
    if (res >= N) return;
    const int s  = ssArr[res];
    const int rt = rtArr[res];
    float c[7], sn[7];
    const float* o0p = o0 + (size_t)res * 17;
#pragma unroll
    for (int t = 0; t < 7; ++t) {
        float cr = o0p[2 * t], sr = o0p[2 * t + 1];
        float inv = rsqrtf(fmaxf(cr * cr + sr * sr, 1e-12f));
        c[t] = cr * inv; sn[t] = sr * inv;
    }
    const float* o1p = o1 + (size_t)res * 9;
    float r0x = o1p[0], r0y = o1p[1], r0z = o1p[2];
    float v1x = o1p[3], v1y = o1p[4], v1z = o1p[5];
    float t2x = o1p[6], t2y = o1p[7], t2z = o1p[8];
    float inv0 = rsqrtf(fmaxf(r0x * r0x + r0y * r0y + r0z * r0z, 1e-12f));
    float e0x = r0x * inv0, e0y = r0y * inv0, e0z = r0z * inv0;
    float d01 = e0x * v1x + e0y * v1y + e0z * v1z;
    float u1x = v1x - e0x * d01, u1y = v1y - e0y * d01, u1z = v1z - e0z * d01;
    float inv1 = rsqrtf(fmaxf(u1x * u1x + u1y * u1y + u1z * u1z, 1e-12f));
    float e1x = u1x * inv1, e1y = u1y * inv1, e1z = u1z * inv1;
    float e2x = e0y * e1z - e0z * e1y;
    float e2y = e0z * e1x - e0x * e1z;
    float e2z = e0x * e1y - e0y * e1x;
    const float* pp = pos + (size_t)res * 3;
    float btx = 0.1f * t2x + pp[0];
    float bty = 0.1f * t2y + pp[1];
    float btz = 0.1f * t2z + pp[2];
    const int sr22 = s * NRES + rt;
    const float4* T4 = (const float4*)rigT + (size_t)sr22 * 24;
    float fr[8][12];
    {
        float4 q0 = T4[0], q1 = T4[1], q2 = T4[2];
        float T0[12] = {q0.x, q0.y, q0.z, q0.w, q1.x, q1.y, q1.z, q1.w,
                        q2.x, q2.y, q2.z, q2.w};
#pragma unroll
        for (int i = 0; i < 3; ++i) {
            float a = T0[i * 3 + 0], b = T0[i * 3 + 1], d = T0[i * 3 + 2];
            fr[0][i * 3 + 0] = a * e0x + b * e0y + d * e0z;
            fr[0][i * 3 + 1] = a * e1x + b * e1y + d * e1z;
            fr[0][i * 3 + 2] = a * e2x + b * e2y + d * e2z;
            fr[0][9 + i]     = a * btx + b * bty + d * btz + T0[9 + i];
        }
    }
#pragma unroll
    for (int f = 1; f < 8; ++f) {
        float4 q0 = T4[f * 3 + 0], q1 = T4[f * 3 + 1], q2 = T4[f * 3 + 2];
        float Tf[12] = {q0.x, q0.y, q0.z, q0.w, q1.x, q1.y, q1.z, q1.w,
                        q2.x, q2.y, q2.z, q2.w};
        float cc = c[f - 1], ssn = sn[f - 1];
#pragma unroll
        for (int i = 0; i < 3; ++i) {
            float m1 = Tf[i * 3 + 1], m2 = Tf[i * 3 + 2];
            fr[f][i * 3 + 0] = Tf[i * 3 + 0];
            fr[f][i * 3 + 1] = m1 * cc + m2 * ssn;
            fr[f][i * 3 + 2] = m2 * cc - m1 * ssn;
            fr[f][9 + i]     = Tf[9 + i];
        }
    }
    int tdv[8];
    {
        const int4* tdq = (const int4*)(tdepArr + rt * 8);
        int4 a = tdq[0], b = tdq[1];
        tdv[0] = a.x; tdv[1] = a.y; tdv[2] = a.z; tdv[3] = a.w;
        tdv[4] = b.x; tdv[5] = b.y; tdv[6] = b.z; tdv[7] = b.w;
    }
#pragma unroll
    for (int i = 1; i < 8; ++i) {
        float P[12];
        sel8(fr, tdv[i] & 7, P);
        float Y[12];
#pragma unroll
        for (int k = 0; k < 12; ++k) Y[k] = fr[i][k];
#pragma unroll
        for (int r = 0; r < 3; ++r) {
            float a = P[r * 3 + 0], b = P[r * 3 + 1], d = P[r * 3 + 2];
#pragma unroll
            for (int j = 0; j < 3; ++j)
                fr[i][r * 3 + j] = a * Y[j] + b * Y[3 + j] + d * Y[6 + j];
            fr[i][9 + r] = a * Y[9] + b * Y[10] + d * Y[11] + P[9 + r];
        }
    }
    const float4* G4  = (const float4*)rigG + (size_t)sr22 * 18;
    const int4*   RD4 = (const int4*)(rdepArr + rt * 24);
    float4* OR4 = (float4*)(outR + (size_t)res * 72);
#pragma unroll
    for (int ck = 0; ck < 6; ++ck) {
        int4 rd = RD4[ck];
        float4 g0 = G4[ck * 3 + 0], g1 = G4[ck * 3 + 1], g2 = G4[ck * 3 + 2];
        float P[12];
        float p0x, p0y, p0z, p1x, p1y, p1z, p2x, p2y, p2z, p3x, p3y, p3z;
        sel8(fr, rd.x & 7, P); apply_point(P, g0.x, g0.y, g0.z, p0x, p0y, p0z);
        sel8(fr, rd.y & 7, P); apply_point(P, g0.w, g1.x, g1.y, p1x, p1y, p1z);
        sel8(fr, rd.z & 7, P); apply_point(P, g1.z, g1.w, g2.x, p2x, p2y, p2z);
        sel8(fr, rd.w & 7, P); apply_point(P, g2.y, g2.z, g2.w, p3x, p3y, p3z);
        OR4[ck * 3 + 0] = make_float4(p0x, p0y, p0z, p1x);
        OR4[ck * 3 + 1] = make_float4(p1y, p1z, p2x, p2y);
        OR4[ck * 3 + 2] = make_float4(p2z, p3x, p3y, p3z);
    }
    float4* OF4 = (float4*)(outF + (size_t)res * 12);
    OF4[0] = make_float4(fr[0][0], fr[0][1], fr[0][2], fr[0][3]);
    OF4[1] = make_float4(fr[0][4], fr[0][5], fr[0][6], fr[0][7]);
    OF4[2] = make_float4(fr[0][8], fr[0][9], fr[0][10], fr[0][11]);
}

extern "C" void kernel_launch(void* const* d_in, const int* in_sizes, int n_in,
                              void* d_out, int out_size, void* d_ws, size_t ws_size,
                              hipStream_t stream) {
    const float* o0   = (const float*)d_in[0];
    const float* o1   = (const float*)d_in[1];
    const float* pos  = (const float*)d_in[2];
    const int*   ssA  = (const int*)d_in[3];
    const int*   rtA  = (const int*)d_in[4];
    const float* rigT = (const float*)d_in[5];
    const float* rigG = (const float*)d_in[6];
    const int*   tdep = (const int*)d_in[7];
    const int*   rdep = (const int*)d_in[8];

    const int N = in_sizes[3];
    float* outR = (float*)d_out;
    float* outF = (float*)d_out + (size_t)N * 72;

    const size_t wsNeed = (size_t)N * 192;  // 48 dwords/residue
    if (ws_size >= wsNeed) {
        unsigned* framesPk = (unsigned*)d_ws;
        const int blockA = 256;
        const int gridA  = (N + blockA - 1) / blockA;
        chain_kernel<<<gridA, blockA, 0, stream>>>(o0, o1, pos, ssA, rtA, rigT,
                                                   tdep, framesPk, outF, N);
        const int blockB = 256;
        const long long na = (long long)N * 24;
        const int gridB  = (int)((na + blockB - 1) / blockB);
        atoms_kernel<<<gridB, blockB, 0, stream>>>(ssA, rtA, rigG, rdep,
                                                   framesPk, outR, N);
    } else {
        const int block = 256;
        const int grid  = (N + block - 1) / block;
        model_kernel_mono<<<grid, block, 0, stream>>>(o0, o1, pos, ssA, rtA, rigT,
                                                      rigG, tdep, rdep, outR, outF, N);
    }
}